// Round 9
// baseline (1035.267 us; speedup 1.0000x reference)
//
#include <hip/hip_runtime.h>
#include <math.h>

constexpr int kDM   = 512;
constexpr int kDI   = 1024;
constexpr int kDS   = 16;
constexpr int kDC   = 4;
constexpr int kDTR  = 32;
constexpr int kL    = 2;
constexpr int kB    = 4;
constexpr int kN    = 1024;
constexpr int kB2   = 8;              // combined batch: rows 0-3 fwd, 4-7 bwd
constexpr int kROWS = kB2 * kN;       // 8192
constexpr int kMDIR = kB * kN;        // 4096 rows per direction

enum { EPI_NONE=0, EPI_SOFTPLUS=1, EPI_RESID=2, EPI_GELU=3, EPI_RESID_BIAS=4, EPI_TANH=5 };
enum { MODE_N=0, MODE_OTR=1, MODE_DBL=2, MODE_GATE=3 };

typedef __attribute__((ext_vector_type(8))) short bf16x8;
typedef __attribute__((ext_vector_type(4))) short bf16x4;
typedef __attribute__((ext_vector_type(4))) float f32x4;

__device__ __forceinline__ unsigned short f2bf(float f) {
    unsigned int u = __float_as_uint(f);
    return (unsigned short)((u + 0x7FFFu + ((u >> 16) & 1u)) >> 16);
}
__device__ __forceinline__ float b2f(unsigned short u) {
    return __uint_as_float((unsigned int)u << 16);
}
__device__ __forceinline__ bf16x4 pack4(const float* v) {
    union { unsigned short u[4]; bf16x4 t; } p;
#pragma unroll
    for (int j = 0; j < 4; j++) p.u[j] = f2bf(v[j]);
    return p.t;
}

// ------------------------------------------------------- weight prep --------
// Convert all GEMM weights fp32 [L][K][N] -> bf16 [L][N][K] (transposed) so
// the GEMM B-staging is contiguous 16-B bf16 loads with zero conversion math.
struct WJobs { const float* s[13]; };
// job order: f_inw b_inw f_xpw b_xpw f_dtw b_dtw f_ow b_ow f_w1 b_w1 f_w2 b_w2 aw1
constexpr size_t O_INW_F = 0;
constexpr size_t O_INW_B = O_INW_F + 2u*512*2048;
constexpr size_t O_XPW_F = O_INW_B + 2u*512*2048;
constexpr size_t O_XPW_B = O_XPW_F + 2u*1024*64;
constexpr size_t O_DTW_F = O_XPW_B + 2u*1024*64;
constexpr size_t O_DTW_B = O_DTW_F + 2u*32*1024;
constexpr size_t O_OW_F  = O_DTW_B + 2u*32*1024;
constexpr size_t O_OW_B  = O_OW_F  + 2u*1024*512;
constexpr size_t O_W1_F  = O_OW_B  + 2u*1024*512;
constexpr size_t O_W1_B  = O_W1_F  + 2u*512*2048;
constexpr size_t O_W2_F  = O_W1_B  + 2u*512*2048;
constexpr size_t O_W2_B  = O_W2_F  + 2u*2048*512;
constexpr size_t O_AW1   = O_W2_B  + 2u*2048*512;
constexpr size_t O_WTOT  = O_AW1   + 1u*512*256;

__global__ __launch_bounds__(256) void wprep_k(WJobs jobs, unsigned short* __restrict__ dst)
{
    const int wK[13] = {512,512,1024,1024,32,32,1024,1024,512,512,2048,2048,512};
    const int wN[13] = {2048,2048,64,64,1024,1024,512,512,2048,2048,512,512,256};
    const int wL[13] = {2,2,2,2,2,2,2,2,2,2,2,2,1};
    int blk = blockIdx.x;
    int j = 0; int base = 0; size_t doff = 0;
    for (; j < 13; j++) {
        int nb = wL[j] * (wK[j] / 32) * (wN[j] / 32);
        if (blk < base + nb) break;
        base += nb;
        doff += (size_t)wL[j] * wK[j] * wN[j];
    }
    int rel = blk - base;
    int K = wK[j], N = wN[j];
    int tk = K / 32, tn = N / 32;
    int l = rel / (tk * tn); rel -= l * tk * tn;
    int kt = rel / tn, nt = rel - (rel / tn) * tn;
    const float* src = jobs.s[j] + (size_t)l * K * N;
    unsigned short* d = dst + doff + (size_t)l * K * N;
    __shared__ float tl[32][33];
    const int c = threadIdx.x & 31, rg = threadIdx.x >> 5;
#pragma unroll
    for (int rr = 0; rr < 4; rr++)
        tl[rg * 4 + rr][c] = src[(size_t)(kt * 32 + rg * 4 + rr) * N + nt * 32 + c];
    __syncthreads();
#pragma unroll
    for (int rr = 0; rr < 4; rr++)
        d[(size_t)(nt * 32 + rg * 4 + rr) * K + kt * 32 + c] = f2bf(tl[c][rg * 4 + rr]);
}

// ---------------------------------------------------------------- init h ----
__global__ __launch_bounds__(256) void init_h_k(const float* __restrict__ x,
                                                float* __restrict__ h)
{
    size_t idx = (size_t)blockIdx.x * 256 + threadIdx.x;   // kROWS*kDM
    int d  = idx & (kDM - 1);
    int t  = (idx >> 9) & (kN - 1);
    int bb = (int)(idx >> 19);
    int b = bb & 3, dir = bb >> 2;
    int ts = dir ? (kN - 1 - t) : t;
    h[idx] = x[((size_t)b * kN + ts) * kDM + d];
}

__global__ __launch_bounds__(256) void h2b_k(const float* __restrict__ h,
                                             unsigned short* __restrict__ o)
{
    size_t idx = (size_t)blockIdx.x * 256 + threadIdx.x;
    o[idx] = f2bf(h[idx]);
}

// ---------------------------------------------------------------- layernorm --
template<int DIM, int OBF>
__global__ __launch_bounds__(256) void ln_k(const float* __restrict__ x,
    const float* __restrict__ wf, const float* __restrict__ wb,
    const float* __restrict__ bf, const float* __restrict__ bbp,
    void* __restrict__ outv)
{
    const int row = blockIdx.x;
    const int tid = threadIdx.x;
    constexpr int PT = DIM / 256;
    const int dir = (row >= kMDIR) ? 1 : 0;
    const float* w = dir ? wb : wf;
    const float* b = dir ? bbp : bf;

    float v[PT];
    float s1 = 0.f, s2 = 0.f;
#pragma unroll
    for (int i = 0; i < PT; i++) {
        float t = x[(size_t)row * DIM + tid + i * 256];
        v[i] = t; s1 += t; s2 += t * t;
    }
    for (int o = 32; o > 0; o >>= 1) { s1 += __shfl_xor(s1, o, 64); s2 += __shfl_xor(s2, o, 64); }
    __shared__ float r1[4], r2[4];
    int wv = tid >> 6;
    if ((tid & 63) == 0) { r1[wv] = s1; r2[wv] = s2; }
    __syncthreads();
    s1 = r1[0] + r1[1] + r1[2] + r1[3];
    s2 = r2[0] + r2[1] + r2[2] + r2[3];
    float mu  = s1 / DIM;
    float var = s2 / DIM - mu * mu;
    float rr  = rsqrtf(var + 1e-5f);
#pragma unroll
    for (int i = 0; i < PT; i++) {
        int c = tid + i * 256;
        float o = (v[i] - mu) * rr * w[c] + b[c];
        if (OBF) ((unsigned short*)outv)[(size_t)row * DIM + c] = f2bf(o);
        else     ((float*)outv)[(size_t)row * DIM + c] = o;
    }
}

// ---------------------------------------------------------------- MFMA GEMM -
// C = A @ B (+bias)(+epilogue). A bf16 [M][lda] (ATR=1: At[K][lda]),
// B^T bf16 [N][K] (pre-transposed weights). All staging = contiguous bf16
// loads, direct LDS writes (no conversion). C fp32 for residual adds
// (OBF=0), bf16 otherwise (OBF=1). Ct outputs always bf16 transposed.
template<int BM, int BN, int EPI, int ATR, int MODE, int OBF>
__global__ __launch_bounds__(256) void gemm_mfma(
    const unsigned short* __restrict__ A, int lda, int K,
    const unsigned short* __restrict__ Btf, const unsigned short* __restrict__ Btb,
    const float* __restrict__ biasf, const float* __restrict__ biasb,
    void* __restrict__ Cv, int ldc, unsigned short* __restrict__ Ct)
{
    constexpr int BK  = 32;
    constexpr int SK  = 40;              // padded LDS row stride (bf16 elems)
    constexpr int WM  = BM / 2, WN = BN / 2;
    constexpr int MT  = WM / 16, NT = WN / 16;
    constexpr int ASL = (BM * BK) / (256 * 8);
    constexpr int BSL = (BN * BK) / (256 * 8);
    constexpr int MB4 = BM / 4;

    __shared__ unsigned short As[BM * SK];
    __shared__ unsigned short Bs[BN * SK];

    const int tid  = threadIdx.x;
    const int n0   = blockIdx.x * BN;
    const int row0 = blockIdx.y * BM;
    const int dir  = (row0 >= kMDIR) ? 1 : 0;
    const unsigned short* __restrict__ Bt = dir ? Btb : Btf;
    const float* bias = dir ? biasb : biasf;

    const int lane = tid & 63;
    const int wave = tid >> 6;
    const int wr = wave >> 1, wc = wave & 1;
    const int ml = lane & 15, q = lane >> 4;

    f32x4 acc[MT][NT];
#pragma unroll
    for (int i = 0; i < MT; i++)
#pragma unroll
        for (int j = 0; j < NT; j++)
#pragma unroll
            for (int r = 0; r < 4; r++) acc[i][j][r] = 0.f;

    const int  mb   = tid & (MB4 - 1);
    const int  ka   = tid / MB4;
    const bool aact = (ka < BK / 4);

    for (int kt = 0; kt < K; kt += BK) {
        // ---- global loads ----
        bf16x8 a_ld[ASL ? ASL : 1];
        bf16x4 at_ld[4];
        if (!ATR) {
#pragma unroll
            for (int r = 0; r < ASL; r++) {
                int i = tid + r * 256;
                int m = i >> 2, c8 = (i & 3) * 8;
                a_ld[r] = *(const bf16x8*)(A + (size_t)(row0 + m) * lda + kt + c8);
            }
        } else if (aact) {
#pragma unroll
            for (int j = 0; j < 4; j++)
                at_ld[j] = *(const bf16x4*)(A + (size_t)(kt + ka * 4 + j) * lda + row0 + mb * 4);
        }
        bf16x8 b_ld[BSL ? BSL : 1];
#pragma unroll
        for (int r = 0; r < BSL; r++) {
            int i = tid + r * 256;
            int n = i >> 2, c8 = (i & 3) * 8;
            b_ld[r] = *(const bf16x8*)(Bt + (size_t)(n0 + n) * K + kt + c8);
        }
        __syncthreads();     // previous iteration's LDS reads complete
        // ---- LDS writes ----
        if (!ATR) {
#pragma unroll
            for (int r = 0; r < ASL; r++) {
                int i = tid + r * 256;
                int m = i >> 2, c8 = (i & 3) * 8;
                *(bf16x8*)&As[m * SK + c8] = a_ld[r];
            }
        } else if (aact) {
            union { bf16x4 v; unsigned short u[4]; } rw4[4];
#pragma unroll
            for (int j = 0; j < 4; j++) rw4[j].v = at_ld[j];
#pragma unroll
            for (int mp = 0; mp < 4; mp++) {
                union { unsigned short u[4]; bf16x4 v; } cl;
#pragma unroll
                for (int j = 0; j < 4; j++) cl.u[j] = rw4[j].u[mp];
                *(bf16x4*)&As[(mb * 4 + mp) * SK + ka * 4] = cl.v;
            }
        }
#pragma unroll
        for (int r = 0; r < BSL; r++) {
            int i = tid + r * 256;
            int n = i >> 2, c8 = (i & 3) * 8;
            *(bf16x8*)&Bs[n * SK + c8] = b_ld[r];
        }
        __syncthreads();
        // ---- fragments + MFMA ----
        bf16x8 af[MT], bfr[NT];
#pragma unroll
        for (int i = 0; i < MT; i++)
            af[i] = *(bf16x8*)&As[(wr * WM + i * 16 + ml) * SK + q * 8];
#pragma unroll
        for (int j = 0; j < NT; j++)
            bfr[j] = *(bf16x8*)&Bs[(wc * WN + j * 16 + ml) * SK + q * 8];
#pragma unroll
        for (int i = 0; i < MT; i++)
#pragma unroll
            for (int j = 0; j < NT; j++)
                acc[i][j] = __builtin_amdgcn_mfma_f32_16x16x32_bf16(af[i], bfr[j], acc[i][j], 0, 0, 0);
    }

    // ---- epilogue ----
    float* Cf = (float*)Cv;
    unsigned short* Cb = (unsigned short*)Cv;
#pragma unroll
    for (int j = 0; j < NT; j++) {
        int col = n0 + wc * WN + j * 16 + ml;
        float bv = 0.f;
        if (EPI == EPI_SOFTPLUS || EPI == EPI_GELU || EPI == EPI_RESID_BIAS || EPI == EPI_TANH)
            bv = bias[col];
#pragma unroll
        for (int i = 0; i < MT; i++) {
            int rw = row0 + wr * WM + i * 16 + q * 4;
            float v4[4];
#pragma unroll
            for (int r = 0; r < 4; r++) {
                float v = acc[i][j][r] + bv;
                if (EPI == EPI_SOFTPLUS) v = (v > 20.f) ? v : __logf(1.f + __expf(v));
                if (EPI == EPI_GELU)     v = 0.5f * v * (1.f + erff(v * 0.70710678118654752f));
                if (EPI == EPI_TANH)     v = tanhf(v);
                v4[r] = v;
            }
            if (MODE == MODE_OTR) {
                *(bf16x4*)&Ct[(size_t)col * kROWS + rw] = pack4(v4);
            } else if (MODE == MODE_GATE && n0 >= kDI) {
#pragma unroll
                for (int r = 0; r < 4; r++) v4[r] = v4[r] / (1.f + __expf(-v4[r]));
                *(bf16x4*)&Ct[(size_t)(col - kDI) * kROWS + rw] = pack4(v4);
            } else {
#pragma unroll
                for (int r = 0; r < 4; r++) {
                    size_t o = (size_t)(rw + r) * ldc + col;
                    if (EPI == EPI_RESID || EPI == EPI_RESID_BIAS) Cf[o] += v4[r];
                    else if (OBF) Cb[o] = f2bf(v4[r]);
                    else Cf[o] = v4[r];
                }
                if (MODE == MODE_DBL && col >= 32)
                    *(bf16x4*)&Ct[(size_t)(col - 32) * kROWS + rw] = pack4(v4);
            }
        }
    }
}

// ---------------------------------------------------------------- conv ------
// xb bf16 [row][kDI] (x-half) -> xhT bf16 [d][row] = silu(causal conv + cb).
__global__ __launch_bounds__(256) void conv_t_k(const unsigned short* __restrict__ xb,
    const float* __restrict__ cwf, const float* __restrict__ cwb,
    const float* __restrict__ cbf, const float* __restrict__ cbb,
    unsigned short* __restrict__ xhT)
{
    __shared__ float tl[67][33];
    const int t0 = blockIdx.x * 64, d0 = blockIdx.y * 32, bb = blockIdx.z;
    const int dir = bb >> 2;
    const float* cw = dir ? cwb : cwf;
    const float* cb = dir ? cbb : cbf;
    const int dl = threadIdx.x & 31, rl = threadIdx.x >> 5;
    const size_t base = (size_t)bb * kN * kDI + d0 + dl;
#pragma unroll
    for (int p = 0; p < 9; p++) {
        int r = p * 8 + rl;
        if (r < 67) {
            int ts = t0 + r - 3;
            tl[r][dl] = (ts >= 0) ? b2f(xb[base + (size_t)ts * kDI]) : 0.f;
        }
    }
    __syncthreads();
    const int gd = d0 + dl;
    float c0 = cw[gd*4+0], c1 = cw[gd*4+1], c2 = cw[gd*4+2], c3 = cw[gd*4+3];
    float bv = cb[gd];
    float o[8];
#pragma unroll
    for (int jj = 0; jj < 8; jj++) {
        int tt = rl + 8 * jj;
        float acc = bv + c0*tl[tt][dl] + c1*tl[tt+1][dl] + c2*tl[tt+2][dl] + c3*tl[tt+3][dl];
        o[jj] = acc / (1.f + __expf(-acc));
    }
    __syncthreads();
#pragma unroll
    for (int jj = 0; jj < 8; jj++) tl[rl + 8 * jj][dl] = o[jj];
    __syncthreads();
    const int tb = threadIdx.x & 63, dg = threadIdx.x >> 6;
#pragma unroll
    for (int dd = 0; dd < 8; dd++) {
        int d2 = dg * 8 + dd;
        xhT[(size_t)(d0 + d2) * kROWS + (size_t)bb * kN + t0 + tb] = f2bf(tl[tb][d2]);
    }
}

// ---------------------------------------------------------------- scan ------
// s-folded LDS-staged scan. r8 showed the scan is VALU-issue-bound (66%
// VALUBusy) with 16 s-lanes redundantly running the full recurrence
// (~14 cy per (d,t)). Fold 4 s-values per lane: wave = 16 d x 4 quads,
// in-register fma chain replaces most of the DPP tree (2 quad_perm adds
// remain), dt*xv computed once per lane, exp2f on prefolded a*log2e maps
// to bare v_exp_f32. ~5 cy/(d,t). Block = 1 wave (64 thr), 512 blocks.
constexpr int kTC   = 16;          // timesteps per chunk
constexpr int kNC   = kN / kTC;    // 64 chunks
constexpr int kPadT = 20;          // [d][t] LDS row stride (floats)
constexpr int kPadS = 20;          // [t][s] LDS row stride (floats)

template<int CTRL>
__device__ __forceinline__ float qp_add(float x) {
    int m = __builtin_amdgcn_update_dpp(0, __float_as_int(x), CTRL, 0xF, 0xF, true);
    return x + __int_as_float(m);
}

__global__ __launch_bounds__(64) void scan_k(
    const unsigned short* __restrict__ dtT, const unsigned short* __restrict__ xhT,
    const unsigned short* __restrict__ gateT, const unsigned short* __restrict__ dblT,
    unsigned short* __restrict__ yT,
    const float* __restrict__ alogf, const float* __restrict__ alogb,
    const float* __restrict__ ddf,   const float* __restrict__ ddb)
{
    __shared__ float DT[2][16 * kPadT], XV[2][16 * kPadT], GV[2][16 * kPadT];
    __shared__ float BT[2][16 * kPadS], CT[2][16 * kPadS];   // [t][s]

    const int blk  = blockIdx.x;          // 512 blocks
    const int bb   = blk >> 6;
    const int dgrp = blk & 63;
    const int lane = threadIdx.x;         // 64
    const int dl   = lane >> 2;           // 16 d per wave
    const int sg   = lane & 3;            // 4 s-values per lane: s = sg*4+j
    const int d    = dgrp * 16 + dl;
    const int dir  = bb >> 2;
    const float* alog = dir ? alogb : alogf;
    const float* ddp  = dir ? ddb : ddf;
    float a2[4];
    {
        float4 al = *(const float4*)&alog[d * kDS + sg * 4];
        const float* alp = &al.x;
#pragma unroll
        for (int j = 0; j < 4; j++)
            a2[j] = -__expf(alp[j]) * 1.4426950408889634f;   // fold log2e for exp2
    }
    const float ddv = ddp[d];
    float hst[4] = {0.f, 0.f, 0.f, 0.f};
    const size_t tb = (size_t)bb * kN;

    // staging role: row rs (16 rows of a tile), t-quad tq
    const int rs = lane >> 2, tq = lane & 3;
    const unsigned short* g_dt = dtT   + (size_t)(dgrp * 16 + rs) * kROWS + tb + tq * 4;
    const unsigned short* g_xv = xhT   + (size_t)(dgrp * 16 + rs) * kROWS + tb + tq * 4;
    const unsigned short* g_gv = gateT + (size_t)(dgrp * 16 + rs) * kROWS + tb + tq * 4;
    const unsigned short* g_B  = dblT  + (size_t)rs * kROWS + tb + tq * 4;        // s=rs
    const unsigned short* g_C  = dblT  + (size_t)(16 + rs) * kROWS + tb + tq * 4;

    unsigned short* py = yT + (size_t)d * kROWS + tb;

#define STAGE(BUF, VDT, VXV, VGV, VB, VC) do {                                   \
        float4 f;                                                                \
        f = make_float4(b2f((VDT).x), b2f((VDT).y), b2f((VDT).z), b2f((VDT).w)); \
        *(float4*)&DT[BUF][rs * kPadT + tq * 4] = f;                             \
        f = make_float4(b2f((VXV).x), b2f((VXV).y), b2f((VXV).z), b2f((VXV).w)); \
        *(float4*)&XV[BUF][rs * kPadT + tq * 4] = f;                             \
        f = make_float4(b2f((VGV).x), b2f((VGV).y), b2f((VGV).z), b2f((VGV).w)); \
        *(float4*)&GV[BUF][rs * kPadT + tq * 4] = f;                             \
        BT[BUF][(tq * 4 + 0) * kPadS + rs] = b2f((VB).x);                        \
        BT[BUF][(tq * 4 + 1) * kPadS + rs] = b2f((VB).y);                        \
        BT[BUF][(tq * 4 + 2) * kPadS + rs] = b2f((VB).z);                        \
        BT[BUF][(tq * 4 + 3) * kPadS + rs] = b2f((VB).w);                        \
        CT[BUF][(tq * 4 + 0) * kPadS + rs] = b2f((VC).x);                        \
        CT[BUF][(tq * 4 + 1) * kPadS + rs] = b2f((VC).y);                        \
        CT[BUF][(tq * 4 + 2) * kPadS + rs] = b2f((VC).z);                        \
        CT[BUF][(tq * 4 + 3) * kPadS + rs] = b2f((VC).w);                        \
    } while (0)

    {
        ushort4 p0 = *(const ushort4*)g_dt, p1 = *(const ushort4*)g_xv,
                p2 = *(const ushort4*)g_gv, p3 = *(const ushort4*)g_B,
                p4 = *(const ushort4*)g_C;
        STAGE(0, p0, p1, p2, p3, p4);
    }
    __syncthreads();

    for (int c = 0; c < kNC; c++) {
        const int buf = c & 1;
        ushort4 q0{}, q1{}, q2{}, q3{}, q4{};
        if (c + 1 < kNC) {
            const int off = (c + 1) * kTC;
            q0 = *(const ushort4*)(g_dt + off);
            q1 = *(const ushort4*)(g_xv + off);
            q2 = *(const ushort4*)(g_gv + off);
            q3 = *(const ushort4*)(g_B + off);
            q4 = *(const ushort4*)(g_C + off);
        }
#pragma unroll
        for (int j0 = 0; j0 < kTC; j0 += 4) {
            float4 dt4 = *(float4*)&DT[buf][dl * kPadT + j0];
            float4 xv4 = *(float4*)&XV[buf][dl * kPadT + j0];
            float4 gv4 = *(float4*)&GV[buf][dl * kPadT + j0];
            const float* dtp = &dt4.x; const float* xvp = &xv4.x;
            const float* gvp = &gv4.x;
            float yv[4];
#pragma unroll
            for (int j = 0; j < 4; j++) {
                const int t = j0 + j;
                float4 B4 = *(float4*)&BT[buf][t * kPadS + sg * 4];
                float4 C4 = *(float4*)&CT[buf][t * kPadS + sg * 4];
                const float* Bp = &B4.x; const float* Cp = &C4.x;
                const float dtv = dtp[j];
                const float dxv = dtv * xvp[j];
                float p = 0.f;
#pragma unroll
                for (int k = 0; k < 4; k++) {
                    float e = exp2f(dtv * a2[k]);        // v_exp_f32 native
                    hst[k] = e * hst[k] + dxv * Bp[k];
                    p += hst[k] * Cp[k];
                }
                p = qp_add<0xB1>(p);   // quad_perm [1,0,3,2]: xor 1
                p = qp_add<0x4E>(p);   // quad_perm [2,3,0,1]: xor 2
                yv[j] = (p + ddv * xvp[j]) * gvp[j];
            }
            if (sg == 0)
                *(bf16x4*)(py + c * kTC + j0) = pack4(yv);
        }
        if (c + 1 < kNC)
            STAGE(buf ^ 1, q0, q1, q2, q3, q4);
        __syncthreads();
    }
#undef STAGE
}

// ---------------------------------------------------------------- attention -
__global__ __launch_bounds__(64) void att_score_k(const unsigned short* __restrict__ tmp,
    const float* __restrict__ aw2, const float* __restrict__ ab2,
    float* __restrict__ score)
{
    int row = blockIdx.x, lane = threadIdx.x;
    float acc = 0.f;
#pragma unroll
    for (int j = 0; j < 4; j++)
        acc += b2f(tmp[(size_t)row * 256 + lane + j * 64]) * aw2[lane + j * 64];
    for (int o = 32; o > 0; o >>= 1) acc += __shfl_xor(acc, o, 64);
    if (lane == 0) score[row] = acc + ab2[0];
}

__global__ __launch_bounds__(256) void softmax_k(const float* __restrict__ score,
                                                 float* __restrict__ w)
{
    int bb = blockIdx.x, tid = threadIdx.x;
    float v[4]; float m = -1e30f;
#pragma unroll
    for (int i = 0; i < 4; i++) { v[i] = score[bb * kN + tid + i * 256]; m = fmaxf(m, v[i]); }
    for (int o = 32; o > 0; o >>= 1) m = fmaxf(m, __shfl_xor(m, o, 64));
    __shared__ float r1[4], r2[4];
    int wv = tid >> 6;
    if ((tid & 63) == 0) r1[wv] = m;
    __syncthreads();
    m = fmaxf(fmaxf(r1[0], r1[1]), fmaxf(r1[2], r1[3]));
    float s = 0.f;
#pragma unroll
    for (int i = 0; i < 4; i++) { v[i] = __expf(v[i] - m); s += v[i]; }
    for (int o = 32; o > 0; o >>= 1) s += __shfl_xor(s, o, 64);
    if ((tid & 63) == 0) r2[wv] = s;
    __syncthreads();
    s = r2[0] + r2[1] + r2[2] + r2[3];
    float inv = 1.f / s;
#pragma unroll
    for (int i = 0; i < 4; i++) w[bb * kN + tid + i * 256] = v[i] * inv;
}

__global__ __launch_bounds__(512) void pool_k(const float* __restrict__ w,
    const float* __restrict__ h, float* zcat)
{
    int bb = blockIdx.x, chunk = blockIdx.y;   // 8 x 32
    int d = threadIdx.x;
    float acc = 0.f;
    int n0 = chunk * 32;
    for (int n = n0; n < n0 + 32; n++)
        acc += w[bb * kN + n] * h[((size_t)bb * kN + n) * kDM + d];
    int b = bb & 3, dir = bb >> 2;
    atomicAdd(&zcat[b * (2 * kDM) + dir * kDM + d], acc);
}

__global__ __launch_bounds__(256) void att_out_k(const float* __restrict__ w,
                                                 float* __restrict__ out)
{
    int idx = blockIdx.x * 256 + threadIdx.x;  // kB*kN
    int b = idx >> 10, n = idx & 1023;
    out[idx] = 0.5f * (w[b * kN + n] + w[(b + 4) * kN + (kN - 1 - n)]);
}

// ---------------------------------------------------------------- launch ----
extern "C" void kernel_launch(void* const* d_in, const int* in_sizes, int n_in,
                              void* d_out, int out_size, void* d_ws, size_t ws_size,
                              hipStream_t stream)
{
    const float* x = (const float*)d_in[0];
    const float* fp[17]; const float* bp[17];
    for (int i = 0; i < 17; i++) { fp[i] = (const float*)d_in[1 + i]; bp[i] = (const float*)d_in[18 + i]; }
    const float* aw1 = (const float*)d_in[35];
    const float* ab1 = (const float*)d_in[36];
    const float* aw2 = (const float*)d_in[37];
    const float* ab2 = (const float*)d_in[38];
    const float* nw  = (const float*)d_in[39];
    const float* nb  = (const float*)d_in[40];
    float* out = (float*)d_out;

    float* h = (float*)d_ws;                                   // 8192*512 f32
    unsigned short* ub    = (unsigned short*)(h + (size_t)kROWS * kDM);  // 8192*512
    unsigned short* xbuf  = ub    + (size_t)kROWS * kDM;        // 8192*1024 (x-half / yT / ffn1 lo)
    unsigned short* tbuf  = xbuf  + (size_t)kROWS * kDI;        // 8192*1024 (dtT / ffn1 hi / hb)
    unsigned short* xhT   = tbuf  + (size_t)kROWS * kDI;        // 1024*8192
    unsigned short* gateT = xhT   + (size_t)kROWS * kDI;        // 1024*8192
    unsigned short* dbl   = gateT + (size_t)kROWS * kDI;        // 8192*64
    unsigned short* dblT  = dbl   + (size_t)kROWS * 64;         // 32*8192
    float* score = (float*)(dblT + (size_t)32 * kROWS);         // 8192
    float* smw   = score + kROWS;                               // 8192
    float* zcat  = smw   + kROWS;                               // 4096
    unsigned short* wts  = (unsigned short*)(zcat + kB * 2 * kDM);

    // ---- weight prep: fp32 [L][K][N] -> bf16 [L][N][K] (one launch) ----
    WJobs jobs;
    jobs.s[0] = fp[2];  jobs.s[1] = bp[2];
    jobs.s[2] = fp[5];  jobs.s[3] = bp[5];
    jobs.s[4] = fp[6];  jobs.s[5] = bp[6];
    jobs.s[6] = fp[10]; jobs.s[7] = bp[10];
    jobs.s[8] = fp[13]; jobs.s[9] = bp[13];
    jobs.s[10] = fp[15]; jobs.s[11] = bp[15];
    jobs.s[12] = aw1;
    int wblocks = 0;
    {
        const int wK[13] = {512,512,1024,1024,32,32,1024,1024,512,512,2048,2048,512};
        const int wN[13] = {2048,2048,64,64,1024,1024,512,512,2048,2048,512,512,256};
        const int wL[13] = {2,2,2,2,2,2,2,2,2,2,2,2,1};
        for (int j = 0; j < 13; j++) wblocks += wL[j] * (wK[j]/32) * (wN[j]/32);
    }
    wprep_k<<<wblocks, 256, 0, stream>>>(jobs, wts);

    init_h_k<<<kROWS * kDM / 256, 256, 0, stream>>>(x, h);

    for (int l = 0; l < kL; l++) {
        const float *f_n1w = fp[0]  + l * kDM,            *b_n1w = bp[0]  + l * kDM;
        const float *f_n1b = fp[1]  + l * kDM,            *b_n1b = bp[1]  + l * kDM;
        const float *f_cw  = fp[3]  + l * kDI * kDC,      *b_cw  = bp[3]  + l * kDI * kDC;
        const float *f_cb  = fp[4]  + l * kDI,            *b_cb  = bp[4]  + l * kDI;
        const float *f_dtb = fp[7]  + l * kDI,            *b_dtb = bp[7]  + l * kDI;
        const float *f_alog= fp[8]  + l * kDI * kDS,      *b_alog= bp[8]  + l * kDI * kDS;
        const float *f_dd  = fp[9]  + l * kDI,            *b_dd  = bp[9]  + l * kDI;
        const float *f_n2w = fp[11] + l * kDM,            *b_n2w = bp[11] + l * kDM;
        const float *f_n2b = fp[12] + l * kDM,            *b_n2b = bp[12] + l * kDM;
        const float *f_b1  = fp[14] + l * 4 * kDM,        *b_b1  = bp[14] + l * 4 * kDM;
        const float *f_b2  = fp[16] + l * kDM,            *b_b2  = bp[16] + l * kDM;

        const unsigned short *wInwF = wts + O_INW_F + (size_t)l * 2048 * 512;
        const unsigned short *wInwB = wts + O_INW_B + (size_t)l * 2048 * 512;
        const unsigned short *wXpwF = wts + O_XPW_F + (size_t)l * 64 * 1024;
        const unsigned short *wXpwB = wts + O_XPW_B + (size_t)l * 64 * 1024;
        const unsigned short *wDtwF = wts + O_DTW_F + (size_t)l * 1024 * 32;
        const unsigned short *wDtwB = wts + O_DTW_B + (size_t)l * 1024 * 32;
        const unsigned short *wOwF  = wts + O_OW_F  + (size_t)l * 512 * 1024;
        const unsigned short *wOwB  = wts + O_OW_B  + (size_t)l * 512 * 1024;
        const unsigned short *wW1F  = wts + O_W1_F  + (size_t)l * 2048 * 512;
        const unsigned short *wW1B  = wts + O_W1_B  + (size_t)l * 2048 * 512;
        const unsigned short *wW2F  = wts + O_W2_F  + (size_t)l * 512 * 2048;
        const unsigned short *wW2B  = wts + O_W2_B  + (size_t)l * 512 * 2048;

        // u = LN1(h) -> bf16
        ln_k<kDM,1><<<kROWS, 256, 0, stream>>>(h, f_n1w, b_n1w, f_n1b, b_n1b, ub);
        // x-half -> xbuf bf16; z-half -> gateT = silu(z) bf16 transposed
        gemm_mfma<128,128,EPI_NONE,0,MODE_GATE,1><<<dim3(16, 64), 256, 0, stream>>>(
            ub, kDM, kDM, wInwF, wInwB, nullptr, nullptr, xbuf, kDI, gateT);
        // xhT[d][row] = silu(conv(xbuf) + cb)
        conv_t_k<<<dim3(kN/64, kDI/32, kB2), 256, 0, stream>>>(
            xbuf, f_cw, b_cw, f_cb, b_cb, xhT);
        // dbl = xh @ xpw (A = xhT ATR); cols>=32 also -> dblT
        gemm_mfma<64,64,EPI_NONE,1,MODE_DBL,1><<<dim3(1, 128), 256, 0, stream>>>(
            xhT, kROWS, kDI, wXpwF, wXpwB, nullptr, nullptr, dbl, 64, dblT);
        // dtT[d][row] = softplus(dbl[:, :32] @ dtw + dtb) (transposed only)
        gemm_mfma<128,128,EPI_SOFTPLUS,0,MODE_OTR,1><<<dim3(8, 64), 256, 0, stream>>>(
            dbl, 64, kDTR, wDtwF, wDtwB, f_dtb, b_dtb, nullptr, 0, tbuf);
        // s-folded LDS-staged selective scan -> yT bf16 (into xbuf)
        scan_k<<<kB2 * kDI / 16, 64, 0, stream>>>(tbuf, xhT, gateT, dblT, xbuf,
                                                  f_alog, b_alog, f_dd, b_dd);
        // h += y @ ow  (A = yT ATR; 128x64 tile -> 512 blocks for occupancy)
        gemm_mfma<128,64,EPI_RESID,1,MODE_N,0><<<dim3(8, 64), 256, 0, stream>>>(
            xbuf, kROWS, kDI, wOwF, wOwB, nullptr, nullptr, h, kDM, nullptr);
        // u = LN2(h) -> bf16
        ln_k<kDM,1><<<kROWS, 256, 0, stream>>>(h, f_n2w, b_n2w, f_n2b, b_n2b, ub);
        // ffn1: gelu(u @ w1 + b1) -> xbuf..tbuf slab bf16 (8192 x 2048)
        gemm_mfma<128,128,EPI_GELU,0,MODE_N,1><<<dim3(16, 64), 256, 0, stream>>>(
            ub, kDM, kDM, wW1F, wW1B, f_b1, b_b1, xbuf, 4*kDM, nullptr);
        // h += ffn1 @ w2 + b2  (128x64 tile -> 512 blocks)
        gemm_mfma<128,64,EPI_RESID_BIAS,0,MODE_N,0><<<dim3(8, 64), 256, 0, stream>>>(
            xbuf, 4*kDM, 4*kDM, wW2F, wW2B, f_b2, b_b2, h, kDM, nullptr);
    }

    // attention: hb = bf16(h); u = tanh(hb @ aw1 + ab1) bf16
    h2b_k<<<kROWS * kDM / 256, 256, 0, stream>>>(h, tbuf);
    gemm_mfma<128,128,EPI_TANH,0,MODE_N,1><<<dim3(2, 64), 256, 0, stream>>>(
        tbuf, kDM, kDM, wts + O_AW1, wts + O_AW1, ab1, ab1, ub, 256, nullptr);
    att_score_k<<<kROWS, 64, 0, stream>>>(ub, aw2, ab2, score);
    softmax_k<<<kB2, 256, 0, stream>>>(score, smw);
    hipMemsetAsync(zcat, 0, kB * 2 * kDM * sizeof(float), stream);
    pool_k<<<dim3(kB2, 32), 512, 0, stream>>>(smw, h, zcat);
    // out[0:4096] = LN(concat(zf, zb))
    ln_k<2*kDM,0><<<kB, 256, 0, stream>>>(zcat, nw, nw, nb, nb, out);
    // out[4096:8192] = 0.5*(af + flip(ab))
    att_out_k<<<kB * kN / 256, 256, 0, stream>>>(smw, out + kB * 2 * kDM);
}

// Round 10
// 863.063 us; speedup vs baseline: 1.1995x; 1.1995x over previous
//
#include <hip/hip_runtime.h>
#include <math.h>

constexpr int kDM   = 512;
constexpr int kDI   = 1024;
constexpr int kDS   = 16;
constexpr int kDC   = 4;
constexpr int kDTR  = 32;
constexpr int kL    = 2;
constexpr int kB    = 4;
constexpr int kN    = 1024;
constexpr int kB2   = 8;              // combined batch: rows 0-3 fwd, 4-7 bwd
constexpr int kROWS = kB2 * kN;       // 8192
constexpr int kMDIR = kB * kN;        // 4096 rows per direction

enum { EPI_NONE=0, EPI_SOFTPLUS=1, EPI_RESID=2, EPI_GELU=3, EPI_RESID_BIAS=4, EPI_TANH=5 };
enum { MODE_N=0, MODE_OTR=1, MODE_DBL=2, MODE_GATE=3 };

typedef __attribute__((ext_vector_type(8))) short bf16x8;
typedef __attribute__((ext_vector_type(4))) short bf16x4;
typedef __attribute__((ext_vector_type(4))) float f32x4;

__device__ __forceinline__ unsigned short f2bf(float f) {
    unsigned int u = __float_as_uint(f);
    return (unsigned short)((u + 0x7FFFu + ((u >> 16) & 1u)) >> 16);
}
__device__ __forceinline__ float b2f(unsigned short u) {
    return __uint_as_float((unsigned int)u << 16);
}
__device__ __forceinline__ bf16x4 pack4(const float* v) {
    union { unsigned short u[4]; bf16x4 t; } p;
#pragma unroll
    for (int j = 0; j < 4; j++) p.u[j] = f2bf(v[j]);
    return p.t;
}

// ------------------------------------------------------- weight prep --------
// Convert all GEMM weights fp32 [L][K][N] -> bf16 [L][N][K] (transposed) so
// the GEMM B-staging is contiguous 16-B bf16 loads with zero conversion math.
struct WJobs { const float* s[13]; };
// job order: f_inw b_inw f_xpw b_xpw f_dtw b_dtw f_ow b_ow f_w1 b_w1 f_w2 b_w2 aw1
constexpr size_t O_INW_F = 0;
constexpr size_t O_INW_B = O_INW_F + 2u*512*2048;
constexpr size_t O_XPW_F = O_INW_B + 2u*512*2048;
constexpr size_t O_XPW_B = O_XPW_F + 2u*1024*64;
constexpr size_t O_DTW_F = O_XPW_B + 2u*1024*64;
constexpr size_t O_DTW_B = O_DTW_F + 2u*32*1024;
constexpr size_t O_OW_F  = O_DTW_B + 2u*32*1024;
constexpr size_t O_OW_B  = O_OW_F  + 2u*1024*512;
constexpr size_t O_W1_F  = O_OW_B  + 2u*1024*512;
constexpr size_t O_W1_B  = O_W1_F  + 2u*512*2048;
constexpr size_t O_W2_F  = O_W1_B  + 2u*512*2048;
constexpr size_t O_W2_B  = O_W2_F  + 2u*2048*512;
constexpr size_t O_AW1   = O_W2_B  + 2u*2048*512;
constexpr size_t O_WTOT  = O_AW1   + 1u*512*256;

__global__ __launch_bounds__(256) void wprep_k(WJobs jobs, unsigned short* __restrict__ dst)
{
    const int wK[13] = {512,512,1024,1024,32,32,1024,1024,512,512,2048,2048,512};
    const int wN[13] = {2048,2048,64,64,1024,1024,512,512,2048,2048,512,512,256};
    const int wL[13] = {2,2,2,2,2,2,2,2,2,2,2,2,1};
    int blk = blockIdx.x;
    int j = 0; int base = 0; size_t doff = 0;
    for (; j < 13; j++) {
        int nb = wL[j] * (wK[j] / 32) * (wN[j] / 32);
        if (blk < base + nb) break;
        base += nb;
        doff += (size_t)wL[j] * wK[j] * wN[j];
    }
    int rel = blk - base;
    int K = wK[j], N = wN[j];
    int tk = K / 32, tn = N / 32;
    int l = rel / (tk * tn); rel -= l * tk * tn;
    int kt = rel / tn, nt = rel - (rel / tn) * tn;
    const float* src = jobs.s[j] + (size_t)l * K * N;
    unsigned short* d = dst + doff + (size_t)l * K * N;
    __shared__ float tl[32][33];
    const int c = threadIdx.x & 31, rg = threadIdx.x >> 5;
#pragma unroll
    for (int rr = 0; rr < 4; rr++)
        tl[rg * 4 + rr][c] = src[(size_t)(kt * 32 + rg * 4 + rr) * N + nt * 32 + c];
    __syncthreads();
#pragma unroll
    for (int rr = 0; rr < 4; rr++)
        d[(size_t)(nt * 32 + rg * 4 + rr) * K + kt * 32 + c] = f2bf(tl[c][rg * 4 + rr]);
}

// ---------------------------------------------------------------- init h ----
__global__ __launch_bounds__(256) void init_h_k(const float* __restrict__ x,
                                                float* __restrict__ h)
{
    size_t idx = (size_t)blockIdx.x * 256 + threadIdx.x;   // kROWS*kDM
    int d  = idx & (kDM - 1);
    int t  = (idx >> 9) & (kN - 1);
    int bb = (int)(idx >> 19);
    int b = bb & 3, dir = bb >> 2;
    int ts = dir ? (kN - 1 - t) : t;
    h[idx] = x[((size_t)b * kN + ts) * kDM + d];
}

__global__ __launch_bounds__(256) void h2b_k(const float* __restrict__ h,
                                             unsigned short* __restrict__ o)
{
    size_t idx = (size_t)blockIdx.x * 256 + threadIdx.x;
    o[idx] = f2bf(h[idx]);
}

// ---------------------------------------------------------------- layernorm --
template<int DIM, int OBF>
__global__ __launch_bounds__(256) void ln_k(const float* __restrict__ x,
    const float* __restrict__ wf, const float* __restrict__ wb,
    const float* __restrict__ bf, const float* __restrict__ bbp,
    void* __restrict__ outv)
{
    const int row = blockIdx.x;
    const int tid = threadIdx.x;
    constexpr int PT = DIM / 256;
    const int dir = (row >= kMDIR) ? 1 : 0;
    const float* w = dir ? wb : wf;
    const float* b = dir ? bbp : bf;

    float v[PT];
    float s1 = 0.f, s2 = 0.f;
#pragma unroll
    for (int i = 0; i < PT; i++) {
        float t = x[(size_t)row * DIM + tid + i * 256];
        v[i] = t; s1 += t; s2 += t * t;
    }
    for (int o = 32; o > 0; o >>= 1) { s1 += __shfl_xor(s1, o, 64); s2 += __shfl_xor(s2, o, 64); }
    __shared__ float r1[4], r2[4];
    int wv = tid >> 6;
    if ((tid & 63) == 0) { r1[wv] = s1; r2[wv] = s2; }
    __syncthreads();
    s1 = r1[0] + r1[1] + r1[2] + r1[3];
    s2 = r2[0] + r2[1] + r2[2] + r2[3];
    float mu  = s1 / DIM;
    float var = s2 / DIM - mu * mu;
    float rr  = rsqrtf(var + 1e-5f);
#pragma unroll
    for (int i = 0; i < PT; i++) {
        int c = tid + i * 256;
        float o = (v[i] - mu) * rr * w[c] + b[c];
        if (OBF) ((unsigned short*)outv)[(size_t)row * DIM + c] = f2bf(o);
        else     ((float*)outv)[(size_t)row * DIM + c] = o;
    }
}

// ---------------------------------------------------------------- MFMA GEMM -
// C = A @ B (+bias)(+epilogue). A bf16 [M][lda] (ATR=1: At[K][lda]),
// B^T bf16 [N][K] (pre-transposed weights).
// KB = K staged per barrier pair (32 or 64). KB=64 halves the
// vmcnt(0)+barrier drains (the ~20% structural stall of the 2-barrier
// K-loop). LDS keeps KB/32 separate SK=40 sub-tiles so the bank-free
// fragment pattern is unchanged.
template<int BM, int BN, int EPI, int ATR, int MODE, int OBF, int KB>
__global__ __launch_bounds__(256) void gemm_mfma(
    const unsigned short* __restrict__ A, int lda, int K,
    const unsigned short* __restrict__ Btf, const unsigned short* __restrict__ Btb,
    const float* __restrict__ biasf, const float* __restrict__ biasb,
    void* __restrict__ Cv, int ldc, unsigned short* __restrict__ Ct)
{
    constexpr int SK  = 40;              // padded LDS row stride (bf16 elems)
    constexpr int KT  = KB / 32;         // 32-wide sub-tiles per stage
    constexpr int CPR = KB / 8;          // 8-elem chunks per row
    constexpr int WM  = BM / 2, WN = BN / 2;
    constexpr int MT  = WM / 16, NT = WN / 16;
    constexpr int ASL = (BM * KB) / (256 * 8);
    constexpr int BSL = (BN * KB) / (256 * 8);
    constexpr int MB4 = BM / 4;
    constexpr int ATR_TH = (BM / 4) * (KB / 4);
    constexpr int ATR_R  = (ATR_TH + 255) / 256;

    __shared__ unsigned short As[KT * BM * SK];
    __shared__ unsigned short Bs[KT * BN * SK];

    const int tid  = threadIdx.x;
    const int n0   = blockIdx.x * BN;
    const int row0 = blockIdx.y * BM;
    const int dir  = (row0 >= kMDIR) ? 1 : 0;
    const unsigned short* __restrict__ Bt = dir ? Btb : Btf;
    const float* bias = dir ? biasb : biasf;

    const int lane = tid & 63;
    const int wave = tid >> 6;
    const int wr = wave >> 1, wc = wave & 1;
    const int ml = lane & 15, q = lane >> 4;

    f32x4 acc[MT][NT];
#pragma unroll
    for (int i = 0; i < MT; i++)
#pragma unroll
        for (int j = 0; j < NT; j++)
#pragma unroll
            for (int r = 0; r < 4; r++) acc[i][j][r] = 0.f;

    for (int kt = 0; kt < K; kt += KB) {
        // ---- global loads ----
        bf16x8 a_ld[ASL ? ASL : 1];
        bf16x4 at_ld[ATR_R][4];
        if (!ATR) {
#pragma unroll
            for (int r = 0; r < ASL; r++) {
                int i = tid + r * 256;
                int m = i / CPR, c8 = (i % CPR) * 8;
                a_ld[r] = *(const bf16x8*)(A + (size_t)(row0 + m) * lda + kt + c8);
            }
        } else {
#pragma unroll
            for (int r = 0; r < ATR_R; r++) {
                int idx = tid + r * 256;
                if (idx < ATR_TH) {
                    int mb = idx % MB4, ka = idx / MB4;
#pragma unroll
                    for (int j = 0; j < 4; j++)
                        at_ld[r][j] = *(const bf16x4*)(A + (size_t)(kt + ka * 4 + j) * lda + row0 + mb * 4);
                }
            }
        }
        bf16x8 b_ld[BSL ? BSL : 1];
#pragma unroll
        for (int r = 0; r < BSL; r++) {
            int i = tid + r * 256;
            int n = i / CPR, c8 = (i % CPR) * 8;
            b_ld[r] = *(const bf16x8*)(Bt + (size_t)(n0 + n) * K + kt + c8);
        }
        __syncthreads();     // previous iteration's LDS reads complete
        // ---- LDS writes ----
        if (!ATR) {
#pragma unroll
            for (int r = 0; r < ASL; r++) {
                int i = tid + r * 256;
                int m = i / CPR, c8 = (i % CPR) * 8;
                *(bf16x8*)&As[((c8 >> 5) * BM + m) * SK + (c8 & 31)] = a_ld[r];
            }
        } else {
#pragma unroll
            for (int r = 0; r < ATR_R; r++) {
                int idx = tid + r * 256;
                if (idx < ATR_TH) {
                    int mb = idx % MB4, ka = idx / MB4;
                    union { bf16x4 v; unsigned short u[4]; } rw4[4];
#pragma unroll
                    for (int j = 0; j < 4; j++) rw4[j].v = at_ld[r][j];
                    int col = ka * 4;
#pragma unroll
                    for (int mp = 0; mp < 4; mp++) {
                        union { unsigned short u[4]; bf16x4 v; } cl;
#pragma unroll
                        for (int j = 0; j < 4; j++) cl.u[j] = rw4[j].u[mp];
                        *(bf16x4*)&As[((col >> 5) * BM + mb * 4 + mp) * SK + (col & 31)] = cl.v;
                    }
                }
            }
        }
#pragma unroll
        for (int r = 0; r < BSL; r++) {
            int i = tid + r * 256;
            int n = i / CPR, c8 = (i % CPR) * 8;
            *(bf16x8*)&Bs[((c8 >> 5) * BN + n) * SK + (c8 & 31)] = b_ld[r];
        }
        __syncthreads();
        // ---- fragments + MFMA (KT sub-steps of K=32) ----
#pragma unroll
        for (int kk = 0; kk < KT; kk++) {
            bf16x8 af[MT], bfr[NT];
#pragma unroll
            for (int i = 0; i < MT; i++)
                af[i] = *(bf16x8*)&As[(kk * BM + wr * WM + i * 16 + ml) * SK + q * 8];
#pragma unroll
            for (int j = 0; j < NT; j++)
                bfr[j] = *(bf16x8*)&Bs[(kk * BN + wc * WN + j * 16 + ml) * SK + q * 8];
#pragma unroll
            for (int i = 0; i < MT; i++)
#pragma unroll
                for (int j = 0; j < NT; j++)
                    acc[i][j] = __builtin_amdgcn_mfma_f32_16x16x32_bf16(af[i], bfr[j], acc[i][j], 0, 0, 0);
        }
    }

    // ---- epilogue ----
    float* Cf = (float*)Cv;
    unsigned short* Cb = (unsigned short*)Cv;
#pragma unroll
    for (int j = 0; j < NT; j++) {
        int col = n0 + wc * WN + j * 16 + ml;
        float bv = 0.f;
        if (EPI == EPI_SOFTPLUS || EPI == EPI_GELU || EPI == EPI_RESID_BIAS || EPI == EPI_TANH)
            bv = bias[col];
#pragma unroll
        for (int i = 0; i < MT; i++) {
            int rw = row0 + wr * WM + i * 16 + q * 4;
            float v4[4];
#pragma unroll
            for (int r = 0; r < 4; r++) {
                float v = acc[i][j][r] + bv;
                if (EPI == EPI_SOFTPLUS) v = (v > 20.f) ? v : __logf(1.f + __expf(v));
                if (EPI == EPI_GELU)     v = 0.5f * v * (1.f + erff(v * 0.70710678118654752f));
                if (EPI == EPI_TANH)     v = tanhf(v);
                v4[r] = v;
            }
            if (MODE == MODE_OTR) {
                *(bf16x4*)&Ct[(size_t)col * kROWS + rw] = pack4(v4);
            } else if (MODE == MODE_GATE && n0 >= kDI) {
#pragma unroll
                for (int r = 0; r < 4; r++) v4[r] = v4[r] / (1.f + __expf(-v4[r]));
                *(bf16x4*)&Ct[(size_t)(col - kDI) * kROWS + rw] = pack4(v4);
            } else {
#pragma unroll
                for (int r = 0; r < 4; r++) {
                    size_t o = (size_t)(rw + r) * ldc + col;
                    if (EPI == EPI_RESID || EPI == EPI_RESID_BIAS) Cf[o] += v4[r];
                    else if (OBF) Cb[o] = f2bf(v4[r]);
                    else Cf[o] = v4[r];
                }
                if (MODE == MODE_DBL && col >= 32)
                    *(bf16x4*)&Ct[(size_t)(col - 32) * kROWS + rw] = pack4(v4);
            }
        }
    }
}

// ---------------------------------------------------------------- conv ------
// xb bf16 [row][kDI] (x-half) -> xhT bf16 [d][row] = silu(causal conv + cb).
__global__ __launch_bounds__(256) void conv_t_k(const unsigned short* __restrict__ xb,
    const float* __restrict__ cwf, const float* __restrict__ cwb,
    const float* __restrict__ cbf, const float* __restrict__ cbb,
    unsigned short* __restrict__ xhT)
{
    __shared__ float tl[67][33];
    const int t0 = blockIdx.x * 64, d0 = blockIdx.y * 32, bb = blockIdx.z;
    const int dir = bb >> 2;
    const float* cw = dir ? cwb : cwf;
    const float* cb = dir ? cbb : cbf;
    const int dl = threadIdx.x & 31, rl = threadIdx.x >> 5;
    const size_t base = (size_t)bb * kN * kDI + d0 + dl;
#pragma unroll
    for (int p = 0; p < 9; p++) {
        int r = p * 8 + rl;
        if (r < 67) {
            int ts = t0 + r - 3;
            tl[r][dl] = (ts >= 0) ? b2f(xb[base + (size_t)ts * kDI]) : 0.f;
        }
    }
    __syncthreads();
    const int gd = d0 + dl;
    float c0 = cw[gd*4+0], c1 = cw[gd*4+1], c2 = cw[gd*4+2], c3 = cw[gd*4+3];
    float bv = cb[gd];
    float o[8];
#pragma unroll
    for (int jj = 0; jj < 8; jj++) {
        int tt = rl + 8 * jj;
        float acc = bv + c0*tl[tt][dl] + c1*tl[tt+1][dl] + c2*tl[tt+2][dl] + c3*tl[tt+3][dl];
        o[jj] = acc / (1.f + __expf(-acc));
    }
    __syncthreads();
#pragma unroll
    for (int jj = 0; jj < 8; jj++) tl[rl + 8 * jj][dl] = o[jj];
    __syncthreads();
    const int tb = threadIdx.x & 63, dg = threadIdx.x >> 6;
#pragma unroll
    for (int dd = 0; dd < 8; dd++) {
        int d2 = dg * 8 + dd;
        xhT[(size_t)(d0 + d2) * kROWS + (size_t)bb * kN + t0 + tb] = f2bf(tl[tb][d2]);
    }
}

// ---------------------------------------------------------------- scan ------
// r8 LDS-staged single-pass scan (reverted from r9's s-folded version:
// s-folding cut instructions 2.7x but collapsed the wave count to 512 on
// 1024 SIMDs -> latency-exposed, 167us vs 107us. The s=16-lane layout's
// 2048 waves (2/SIMD) are required for latency hiding; this shape's
// ~107us at 66% VALUBusy is near its issue floor.)
constexpr int kTC  = 16;          // timesteps per chunk
constexpr int kNC  = kN / kTC;    // 64 chunks
constexpr int kPad = 20;          // LDS row stride (floats)

template<int CTRL>
__device__ __forceinline__ float dpp_add(float x) {
    int m = __builtin_amdgcn_update_dpp(0, __float_as_int(x), CTRL, 0xF, 0xF, true);
    return x + __int_as_float(m);
}

__global__ __launch_bounds__(256) void scan_k(
    const unsigned short* __restrict__ dtT, const unsigned short* __restrict__ xhT,
    const unsigned short* __restrict__ gateT, const unsigned short* __restrict__ dblT,
    unsigned short* __restrict__ yT,
    const float* __restrict__ alogf, const float* __restrict__ alogb,
    const float* __restrict__ ddf,   const float* __restrict__ ddb)
{
    __shared__ float DT[2][16 * kPad], XV[2][16 * kPad], GV[2][16 * kPad],
                     BT[2][16 * kPad], CT[2][16 * kPad];

    const int blk  = blockIdx.x;          // 512 blocks
    const int bb   = blk >> 6;
    const int dgrp = blk & 63;
    const int s    = threadIdx.x & 15;
    const int dloc = threadIdx.x >> 4;
    const int d    = dgrp * 16 + dloc;
    const int dir  = bb >> 2;
    const float* alog = dir ? alogb : alogf;
    const float* ddp  = dir ? ddb : ddf;
    const float a   = -__expf(alog[d * kDS + s]);
    const float ddv = ddp[d];
    float hst = 0.f;
    const size_t tb = (size_t)bb * kN;

    const int r  = threadIdx.x >> 4;
    const int ct = threadIdx.x & 15;
    const unsigned short* g_dt = dtT   + (size_t)(dgrp * 16 + r) * kROWS + tb + ct;
    const unsigned short* g_xv = xhT   + (size_t)(dgrp * 16 + r) * kROWS + tb + ct;
    const unsigned short* g_gv = gateT + (size_t)(dgrp * 16 + r) * kROWS + tb + ct;
    const unsigned short* g_B  = dblT  + (size_t)r * kROWS + tb + ct;
    const unsigned short* g_C  = dblT  + (size_t)(16 + r) * kROWS + tb + ct;
    const int woff = r * kPad + ct;

    unsigned short* py = yT + (size_t)d * kROWS + tb;

    {
        unsigned short p0 = g_dt[0], p1 = g_xv[0], p2 = g_gv[0], p3 = g_B[0], p4 = g_C[0];
        DT[0][woff] = b2f(p0); XV[0][woff] = b2f(p1); GV[0][woff] = b2f(p2);
        BT[0][woff] = b2f(p3); CT[0][woff] = b2f(p4);
    }
    __syncthreads();

    for (int c = 0; c < kNC; c++) {
        const int buf = c & 1;
        unsigned short q0 = 0, q1 = 0, q2 = 0, q3 = 0, q4 = 0;
        if (c + 1 < kNC) {
            const int off = (c + 1) * kTC;
            q0 = g_dt[off]; q1 = g_xv[off]; q2 = g_gv[off];
            q3 = g_B[off];  q4 = g_C[off];
        }
#pragma unroll
        for (int j0 = 0; j0 < kTC; j0 += 4) {
            float4 dt4 = *(float4*)&DT[buf][dloc * kPad + j0];
            float4 xv4 = *(float4*)&XV[buf][dloc * kPad + j0];
            float4 gv4 = *(float4*)&GV[buf][dloc * kPad + j0];
            float4 B4  = *(float4*)&BT[buf][s * kPad + j0];
            float4 C4  = *(float4*)&CT[buf][s * kPad + j0];
            const float* dtp = &dt4.x; const float* xvp = &xv4.x;
            const float* gvp = &gv4.x; const float* Bp = &B4.x;
            const float* Cp  = &C4.x;
            float yv[4];
#pragma unroll
            for (int j = 0; j < 4; j++) {
                float e = __expf(dtp[j] * a);
                hst = e * hst + (dtp[j] * xvp[j]) * Bp[j];
                float p = hst * Cp[j];
                p = dpp_add<0x128>(p);   // row_ror:8  (16-lane row == s-group)
                p = dpp_add<0x124>(p);   // row_ror:4
                p = dpp_add<0x122>(p);   // row_ror:2
                p = dpp_add<0x121>(p);   // row_ror:1
                yv[j] = (p + ddv * xvp[j]) * gvp[j];
            }
            if (s == 0)
                *(bf16x4*)(py + c * kTC + j0) = pack4(yv);
        }
        if (c + 1 < kNC) {
            const int nb = buf ^ 1;
            DT[nb][woff] = b2f(q0); XV[nb][woff] = b2f(q1); GV[nb][woff] = b2f(q2);
            BT[nb][woff] = b2f(q3); CT[nb][woff] = b2f(q4);
        }
        __syncthreads();
    }
}

// ---------------------------------------------------------------- attention -
__global__ __launch_bounds__(64) void att_score_k(const unsigned short* __restrict__ tmp,
    const float* __restrict__ aw2, const float* __restrict__ ab2,
    float* __restrict__ score)
{
    int row = blockIdx.x, lane = threadIdx.x;
    float acc = 0.f;
#pragma unroll
    for (int j = 0; j < 4; j++)
        acc += b2f(tmp[(size_t)row * 256 + lane + j * 64]) * aw2[lane + j * 64];
    for (int o = 32; o > 0; o >>= 1) acc += __shfl_xor(acc, o, 64);
    if (lane == 0) score[row] = acc + ab2[0];
}

__global__ __launch_bounds__(256) void softmax_k(const float* __restrict__ score,
                                                 float* __restrict__ w)
{
    int bb = blockIdx.x, tid = threadIdx.x;
    float v[4]; float m = -1e30f;
#pragma unroll
    for (int i = 0; i < 4; i++) { v[i] = score[bb * kN + tid + i * 256]; m = fmaxf(m, v[i]); }
    for (int o = 32; o > 0; o >>= 1) m = fmaxf(m, __shfl_xor(m, o, 64));
    __shared__ float r1[4], r2[4];
    int wv = tid >> 6;
    if ((tid & 63) == 0) r1[wv] = m;
    __syncthreads();
    m = fmaxf(fmaxf(r1[0], r1[1]), fmaxf(r1[2], r1[3]));
    float s = 0.f;
#pragma unroll
    for (int i = 0; i < 4; i++) { v[i] = __expf(v[i] - m); s += v[i]; }
    for (int o = 32; o > 0; o >>= 1) s += __shfl_xor(s, o, 64);
    if ((tid & 63) == 0) r2[wv] = s;
    __syncthreads();
    s = r2[0] + r2[1] + r2[2] + r2[3];
    float inv = 1.f / s;
#pragma unroll
    for (int i = 0; i < 4; i++) w[bb * kN + tid + i * 256] = v[i] * inv;
}

__global__ __launch_bounds__(512) void pool_k(const float* __restrict__ w,
    const float* __restrict__ h, float* zcat)
{
    int bb = blockIdx.x, chunk = blockIdx.y;   // 8 x 32
    int d = threadIdx.x;
    float acc = 0.f;
    int n0 = chunk * 32;
    for (int n = n0; n < n0 + 32; n++)
        acc += w[bb * kN + n] * h[((size_t)bb * kN + n) * kDM + d];
    int b = bb & 3, dir = bb >> 2;
    atomicAdd(&zcat[b * (2 * kDM) + dir * kDM + d], acc);
}

__global__ __launch_bounds__(256) void att_out_k(const float* __restrict__ w,
                                                 float* __restrict__ out)
{
    int idx = blockIdx.x * 256 + threadIdx.x;  // kB*kN
    int b = idx >> 10, n = idx & 1023;
    out[idx] = 0.5f * (w[b * kN + n] + w[(b + 4) * kN + (kN - 1 - n)]);
}

// ---------------------------------------------------------------- launch ----
extern "C" void kernel_launch(void* const* d_in, const int* in_sizes, int n_in,
                              void* d_out, int out_size, void* d_ws, size_t ws_size,
                              hipStream_t stream)
{
    const float* x = (const float*)d_in[0];
    const float* fp[17]; const float* bp[17];
    for (int i = 0; i < 17; i++) { fp[i] = (const float*)d_in[1 + i]; bp[i] = (const float*)d_in[18 + i]; }
    const float* aw1 = (const float*)d_in[35];
    const float* ab1 = (const float*)d_in[36];
    const float* aw2 = (const float*)d_in[37];
    const float* ab2 = (const float*)d_in[38];
    const float* nw  = (const float*)d_in[39];
    const float* nb  = (const float*)d_in[40];
    float* out = (float*)d_out;

    float* h = (float*)d_ws;                                   // 8192*512 f32
    unsigned short* ub    = (unsigned short*)(h + (size_t)kROWS * kDM);  // 8192*512
    unsigned short* xbuf  = ub    + (size_t)kROWS * kDM;        // 8192*1024 (x-half / yT / ffn1 lo)
    unsigned short* tbuf  = xbuf  + (size_t)kROWS * kDI;        // 8192*1024 (dtT / ffn1 hi / hb)
    unsigned short* xhT   = tbuf  + (size_t)kROWS * kDI;        // 1024*8192
    unsigned short* gateT = xhT   + (size_t)kROWS * kDI;        // 1024*8192
    unsigned short* dbl   = gateT + (size_t)kROWS * kDI;        // 8192*64
    unsigned short* dblT  = dbl   + (size_t)kROWS * 64;         // 32*8192
    float* score = (float*)(dblT + (size_t)32 * kROWS);         // 8192
    float* smw   = score + kROWS;                               // 8192
    float* zcat  = smw   + kROWS;                               // 4096
    unsigned short* wts  = (unsigned short*)(zcat + kB * 2 * kDM);

    // ---- weight prep: fp32 [L][K][N] -> bf16 [L][N][K] (one launch) ----
    WJobs jobs;
    jobs.s[0] = fp[2];  jobs.s[1] = bp[2];
    jobs.s[2] = fp[5];  jobs.s[3] = bp[5];
    jobs.s[4] = fp[6];  jobs.s[5] = bp[6];
    jobs.s[6] = fp[10]; jobs.s[7] = bp[10];
    jobs.s[8] = fp[13]; jobs.s[9] = bp[13];
    jobs.s[10] = fp[15]; jobs.s[11] = bp[15];
    jobs.s[12] = aw1;
    int wblocks = 0;
    {
        const int wK[13] = {512,512,1024,1024,32,32,1024,1024,512,512,2048,2048,512};
        const int wN[13] = {2048,2048,64,64,1024,1024,512,512,2048,2048,512,512,256};
        const int wL[13] = {2,2,2,2,2,2,2,2,2,2,2,2,1};
        for (int j = 0; j < 13; j++) wblocks += wL[j] * (wK[j]/32) * (wN[j]/32);
    }
    wprep_k<<<wblocks, 256, 0, stream>>>(jobs, wts);

    init_h_k<<<kROWS * kDM / 256, 256, 0, stream>>>(x, h);

    for (int l = 0; l < kL; l++) {
        const float *f_n1w = fp[0]  + l * kDM,            *b_n1w = bp[0]  + l * kDM;
        const float *f_n1b = fp[1]  + l * kDM,            *b_n1b = bp[1]  + l * kDM;
        const float *f_cw  = fp[3]  + l * kDI * kDC,      *b_cw  = bp[3]  + l * kDI * kDC;
        const float *f_cb  = fp[4]  + l * kDI,            *b_cb  = bp[4]  + l * kDI;
        const float *f_dtb = fp[7]  + l * kDI,            *b_dtb = bp[7]  + l * kDI;
        const float *f_alog= fp[8]  + l * kDI * kDS,      *b_alog= bp[8]  + l * kDI * kDS;
        const float *f_dd  = fp[9]  + l * kDI,            *b_dd  = bp[9]  + l * kDI;
        const float *f_n2w = fp[11] + l * kDM,            *b_n2w = bp[11] + l * kDM;
        const float *f_n2b = fp[12] + l * kDM,            *b_n2b = bp[12] + l * kDM;
        const float *f_b1  = fp[14] + l * 4 * kDM,        *b_b1  = bp[14] + l * 4 * kDM;
        const float *f_b2  = fp[16] + l * kDM,            *b_b2  = bp[16] + l * kDM;

        const unsigned short *wInwF = wts + O_INW_F + (size_t)l * 2048 * 512;
        const unsigned short *wInwB = wts + O_INW_B + (size_t)l * 2048 * 512;
        const unsigned short *wXpwF = wts + O_XPW_F + (size_t)l * 64 * 1024;
        const unsigned short *wXpwB = wts + O_XPW_B + (size_t)l * 64 * 1024;
        const unsigned short *wDtwF = wts + O_DTW_F + (size_t)l * 1024 * 32;
        const unsigned short *wDtwB = wts + O_DTW_B + (size_t)l * 1024 * 32;
        const unsigned short *wOwF  = wts + O_OW_F  + (size_t)l * 512 * 1024;
        const unsigned short *wOwB  = wts + O_OW_B  + (size_t)l * 512 * 1024;
        const unsigned short *wW1F  = wts + O_W1_F  + (size_t)l * 2048 * 512;
        const unsigned short *wW1B  = wts + O_W1_B  + (size_t)l * 2048 * 512;
        const unsigned short *wW2F  = wts + O_W2_F  + (size_t)l * 512 * 2048;
        const unsigned short *wW2B  = wts + O_W2_B  + (size_t)l * 512 * 2048;

        // u = LN1(h) -> bf16
        ln_k<kDM,1><<<kROWS, 256, 0, stream>>>(h, f_n1w, b_n1w, f_n1b, b_n1b, ub);
        // x-half -> xbuf bf16; z-half -> gateT = silu(z) bf16 transposed
        gemm_mfma<128,128,EPI_NONE,0,MODE_GATE,1,64><<<dim3(16, 64), 256, 0, stream>>>(
            ub, kDM, kDM, wInwF, wInwB, nullptr, nullptr, xbuf, kDI, gateT);
        // xhT[d][row] = silu(conv(xbuf) + cb)
        conv_t_k<<<dim3(kN/64, kDI/32, kB2), 256, 0, stream>>>(
            xbuf, f_cw, b_cw, f_cb, b_cb, xhT);
        // dbl = xh @ xpw (A = xhT ATR); cols>=32 also -> dblT
        gemm_mfma<64,64,EPI_NONE,1,MODE_DBL,1,64><<<dim3(1, 128), 256, 0, stream>>>(
            xhT, kROWS, kDI, wXpwF, wXpwB, nullptr, nullptr, dbl, 64, dblT);
        // dtT[d][row] = softplus(dbl[:, :32] @ dtw + dtb) (transposed only)
        gemm_mfma<128,128,EPI_SOFTPLUS,0,MODE_OTR,1,32><<<dim3(8, 64), 256, 0, stream>>>(
            dbl, 64, kDTR, wDtwF, wDtwB, f_dtb, b_dtb, nullptr, 0, tbuf);
        // LDS-staged selective scan -> yT bf16 (into xbuf)
        scan_k<<<kB2 * kDI / 16, 256, 0, stream>>>(tbuf, xhT, gateT, dblT, xbuf,
                                                   f_alog, b_alog, f_dd, b_dd);
        // h += y @ ow  (A = yT ATR; 128x64 tile -> 512 blocks for occupancy)
        gemm_mfma<128,64,EPI_RESID,1,MODE_N,0,64><<<dim3(8, 64), 256, 0, stream>>>(
            xbuf, kROWS, kDI, wOwF, wOwB, nullptr, nullptr, h, kDM, nullptr);
        // u = LN2(h) -> bf16
        ln_k<kDM,1><<<kROWS, 256, 0, stream>>>(h, f_n2w, b_n2w, f_n2b, b_n2b, ub);
        // ffn1: gelu(u @ w1 + b1) -> xbuf..tbuf slab bf16 (8192 x 2048)
        gemm_mfma<128,128,EPI_GELU,0,MODE_N,1,64><<<dim3(16, 64), 256, 0, stream>>>(
            ub, kDM, kDM, wW1F, wW1B, f_b1, b_b1, xbuf, 4*kDM, nullptr);
        // h += ffn1 @ w2 + b2  (128x64 tile -> 512 blocks)
        gemm_mfma<128,64,EPI_RESID_BIAS,0,MODE_N,0,64><<<dim3(8, 64), 256, 0, stream>>>(
            xbuf, 4*kDM, 4*kDM, wW2F, wW2B, f_b2, b_b2, h, kDM, nullptr);
    }

    // attention: hb = bf16(h); u = tanh(hb @ aw1 + ab1) bf16
    h2b_k<<<kROWS * kDM / 256, 256, 0, stream>>>(h, tbuf);
    gemm_mfma<128,128,EPI_TANH,0,MODE_N,1,64><<<dim3(2, 64), 256, 0, stream>>>(
        tbuf, kDM, kDM, wts + O_AW1, wts + O_AW1, ab1, ab1, ub, 256, nullptr);
    att_score_k<<<kROWS, 64, 0, stream>>>(ub, aw2, ab2, score);
    softmax_k<<<kB2, 256, 0, stream>>>(score, smw);
    hipMemsetAsync(zcat, 0, kB * 2 * kDM * sizeof(float), stream);
    pool_k<<<dim3(kB2, 32), 512, 0, stream>>>(smw, h, zcat);
    // out[0:4096] = LN(concat(zf, zb))
    ln_k<2*kDM,0><<<kB, 256, 0, stream>>>(zcat, nw, nw, nb, nb, out);
    // out[4096:8192] = 0.5*(af + flip(ab))
    att_out_k<<<kB * kN / 256, 256, 0, stream>>>(smw, out + kB * 2 * kDM);
}